// Round 1
// baseline (1451.922 us; speedup 1.0000x reference)
//
#include <hip/hip_runtime.h>
#include <math.h>

// Problem dims (fixed)
#define Bn 64
#define Tn 512
#define Dn 256
#define Hn 256
#define Gn 1024   // 4*H

typedef _Float16 f16x2 __attribute__((ext_vector_type(2)));

union U32H2 { unsigned int u; f16x2 h; };

__device__ __forceinline__ f16x2 u2h(unsigned int u) { U32H2 v; v.u = u; return v.h; }
__device__ __forceinline__ unsigned int packh2(float x, float y) {
    U32H2 v; v.h = (f16x2){(_Float16)x, (_Float16)y}; return v.u;
}

#if __has_builtin(__builtin_amdgcn_fdot2)
__device__ __forceinline__ float fdot2f(f16x2 a, f16x2 b, float c) {
    return __builtin_amdgcn_fdot2(a, b, c, false);
}
#else
__device__ __forceinline__ float fdot2f(f16x2 a, f16x2 b, float c) {
    return fmaf((float)a[1], (float)b[1], fmaf((float)a[0], (float)b[0], c));
}
#endif

__device__ __forceinline__ float sigm(float x) { return 1.0f / (1.0f + expf(-x)); }

// ---------------------------------------------------------------------------
// W_c[g][k] = sum_d W_ih[g][d] * W_att[d][k];  bias_c[g] = W_ih[g]·b_att + b_ih[g] + b_hh[g]
// grid: 1024 blocks (g), 256 threads (k)
// ---------------------------------------------------------------------------
__global__ void k_wc(const float* __restrict__ W_ih, const float* __restrict__ W_att,
                     const float* __restrict__ b_att, const float* __restrict__ b_ih,
                     const float* __restrict__ b_hh,
                     float* __restrict__ W_c, float* __restrict__ bias_c) {
    int g = blockIdx.x;
    int k = threadIdx.x;
    __shared__ float wih_s[Dn];
    __shared__ float red[256];
    wih_s[k] = W_ih[g * Dn + k];
    __syncthreads();
    float acc = 0.0f;
    for (int d = 0; d < Dn; ++d)
        acc = fmaf(wih_s[d], W_att[d * Dn + k], acc);
    W_c[g * Dn + k] = acc;
    red[k] = wih_s[k] * b_att[k];
    __syncthreads();
    for (int s = 128; s > 0; s >>= 1) {
        if (k < s) red[k] += red[k + s];
        __syncthreads();
    }
    if (k == 0) bias_c[g] = red[0] + b_ih[g] + b_hh[g];
}

// ---------------------------------------------------------------------------
// vlin0[b][d] = values[b,0,:]·W_att[d,:] + b_att[d]   (row 0 only; tiny)
// grid: 64 blocks (b), 256 threads (d)
// ---------------------------------------------------------------------------
__global__ void k_vlin0(const float* __restrict__ values, const float* __restrict__ W_att,
                        const float* __restrict__ b_att, float* __restrict__ vlin0) {
    int b = blockIdx.x, d = threadIdx.x;
    __shared__ float v_s[Dn];
    v_s[d] = values[(size_t)b * Tn * Dn + d];
    __syncthreads();
    float acc = b_att[d];
    for (int k = 0; k < Dn; ++k)
        acc = fmaf(v_s[k], W_att[d * Dn + k], acc);
    vlin0[b * Dn + d] = acc;
}

// ---------------------------------------------------------------------------
// a_tj[b][t] = sigmoid( vlin0[b,:] · values[b,t,:] )
// one wave per (b,t); 4 waves per block; grid = 32768/4 = 8192 blocks
// ---------------------------------------------------------------------------
__global__ void k_atj(const float* __restrict__ values, const float* __restrict__ vlin0,
                      float* __restrict__ a_tj) {
    int wid = threadIdx.x >> 6, lane = threadIdx.x & 63;
    int idx = blockIdx.x * 4 + wid;            // b*T + t
    int b = idx >> 9;
    const float4* vp = (const float4*)(values + (size_t)idx * Dn);
    const float4* qp = (const float4*)(vlin0 + b * Dn);
    float4 v = vp[lane], q = qp[lane];
    float s = v.x * q.x + v.y * q.y + v.z * q.z + v.w * q.w;
    #pragma unroll
    for (int off = 32; off; off >>= 1) s += __shfl_xor(s, off);
    if (lane == 0) a_tj[idx] = 1.0f / (1.0f + expf(-s));
}

// ---------------------------------------------------------------------------
// xW[m][n] = A[m,:] · W_c[n,:] + bias_c[n]   (M=32768, N=1024, K=256), fp32 tiles
// grid: dim3(16, 512)  [bx = N-tile so consecutive blocks share the A panel]
// ---------------------------------------------------------------------------
#define GBK 32
__global__ __launch_bounds__(256) void k_gemm(const float* __restrict__ A,
                                              const float* __restrict__ Bw,
                                              const float* __restrict__ bias,
                                              float* __restrict__ C) {
    __shared__ __align__(16) float As[GBK][68];
    __shared__ __align__(16) float Bs[GBK][68];
    int tid = threadIdx.x;
    int tx = tid & 15, ty = tid >> 4;
    int nBase = blockIdx.x * 64;
    int mBase = blockIdx.y * 64;
    float acc[4][4] = {};
    for (int kb = 0; kb < 256; kb += GBK) {
        #pragma unroll
        for (int i = 0; i < 2; ++i) {
            int li = tid + i * 256;            // 0..511
            int r = li >> 3, kq = (li & 7) * 4;
            float4 av = *(const float4*)(A + (size_t)(mBase + r) * 256 + kb + kq);
            As[kq + 0][r] = av.x; As[kq + 1][r] = av.y;
            As[kq + 2][r] = av.z; As[kq + 3][r] = av.w;
            float4 bv = *(const float4*)(Bw + (size_t)(nBase + r) * 256 + kb + kq);
            Bs[kq + 0][r] = bv.x; Bs[kq + 1][r] = bv.y;
            Bs[kq + 2][r] = bv.z; Bs[kq + 3][r] = bv.w;
        }
        __syncthreads();
        #pragma unroll
        for (int kk = 0; kk < GBK; ++kk) {
            float av[4], bv[4];
            #pragma unroll
            for (int i = 0; i < 4; ++i) av[i] = As[kk][ty * 4 + i];
            #pragma unroll
            for (int i = 0; i < 4; ++i) bv[i] = Bs[kk][tx * 4 + i];
            #pragma unroll
            for (int i = 0; i < 4; ++i)
                #pragma unroll
                for (int j = 0; j < 4; ++j)
                    acc[i][j] = fmaf(av[i], bv[j], acc[i][j]);
        }
        __syncthreads();
    }
    #pragma unroll
    for (int i = 0; i < 4; ++i) {
        int m = mBase + ty * 4 + i;
        #pragma unroll
        for (int j = 0; j < 4; ++j) {
            int n = nBase + tx * 4 + j;
            C[(size_t)m * Gn + n] = acc[i][j] + bias[n];
        }
    }
}

// ---------------------------------------------------------------------------
// Recurrence: one WG per batch. 512 threads; thread t owns gate rows t and t+512.
// W_hh as f16: k in [0,192) in VGPRs (96 f16x2 per row), k in [192,256) in LDS
// (XOR-swizzled [g][32] u32 layout). h exchanged per step as packed f16x2 in LDS.
// ---------------------------------------------------------------------------
#define NPREG 96   // f16 pairs per row in registers (k < 192)
#define NPLDS 32   // f16 pairs per row in LDS      (k >= 192)

__global__ __launch_bounds__(512, 2) void k_rec(
        const float* __restrict__ xW,      // [B,T,1024]  (includes all biases)
        const float* __restrict__ W_hh,    // [1024,256]
        const float* __restrict__ Deltas,  // [B,T,256]
        const float* __restrict__ a_tj,    // [B,T]
        float* __restrict__ out) {         // [B,T,256]
    extern __shared__ __align__(16) char smem[];
    unsigned int* Wl   = (unsigned int*)smem;               // 1024*32*4 = 131072 B
    float*        gate = (float*)(smem + 131072);           // 4096 B
    unsigned int* hpk  = (unsigned int*)(smem + 131072 + 4096); // 512 B

    const int tid = threadIdx.x;
    const int b = blockIdx.x;
    const int g0 = tid, g1 = tid + 512;
    const int sw = (g0 & 7);                // same for g1

    // ---- load register-resident weights (rows g0,g1; k in [0,192)) ----
    f16x2 wlo[NPREG], whi[NPREG];
    {
        const float4* p0 = (const float4*)(W_hh + (size_t)g0 * 256);
        const float4* p1 = (const float4*)(W_hh + (size_t)g1 * 256);
        #pragma unroll
        for (int q = 0; q < 48; ++q) {
            float4 w = p0[q];
            wlo[q * 2 + 0] = (f16x2){(_Float16)w.x, (_Float16)w.y};
            wlo[q * 2 + 1] = (f16x2){(_Float16)w.z, (_Float16)w.w};
            float4 v = p1[q];
            whi[q * 2 + 0] = (f16x2){(_Float16)v.x, (_Float16)v.y};
            whi[q * 2 + 1] = (f16x2){(_Float16)v.z, (_Float16)v.w};
        }
    }
    // ---- cooperative fill of LDS weights (k in [192,256)) ----
    for (int idx = tid; idx < 1024 * NPLDS; idx += 512) {
        int g = idx >> 5, kp = idx & 31;
        float2 w = *(const float2*)(W_hh + (size_t)g * 256 + 192 + kp * 2);
        Wl[g * 32 + (kp ^ ((g & 7) << 2))] = packh2(w.x, w.y);
    }

    // per-unit state (valid for tid < 256)
    const int j = tid;
    float cst = 0.0f, c0 = 0.0f, dcrun = 0.0f;

    // ---- t = 0 (cell with h=0,c=0; carry c stays 0; c_0 stored) ----
    {
        float G0 = xW[((size_t)b * Tn + 0) * Gn + g0];
        float G1 = xW[((size_t)b * Tn + 0) * Gn + g1];
        gate[g0] = G0; gate[g1] = G1;
        if (tid < 256) dcrun = Deltas[((size_t)b * Tn + 0) * Dn + j];
        __syncthreads();
        if (tid < 256) {
            float gi = gate[j], gg = gate[512 + j], go = gate[768 + j];
            c0 = sigm(gi) * tanhf(gg);
            float h = sigm(go) * tanhf(c0);
            out[((size_t)b * Tn + 0) * Hn + j] = h;
            float hn = __shfl_xor(h, 1);
            if ((j & 1) == 0) hpk[j >> 1] = packh2(h, hn);
        }
        __syncthreads();
    }

    // ---- main loop t = 1..511 ----
    for (int t = 1; t < Tn; ++t) {
        // issue global loads early; consumed after the dot product
        float xw0 = xW[((size_t)b * Tn + t) * Gn + g0];
        float xw1 = xW[((size_t)b * Tn + t) * Gn + g1];
        float del = 0.0f, at = 0.0f;
        if (tid < 256) {
            del = Deltas[((size_t)b * Tn + t) * Dn + j];
            at  = a_tj[b * Tn + t];
        }

        float a0a = 0.f, a0b = 0.f, a1a = 0.f, a1b = 0.f;
        const uint4* hp4 = (const uint4*)hpk;
        // register-resident K range [0,192): 24 chunks of 4 pairs
        #pragma unroll
        for (int cch = 0; cch < 24; ++cch) {
            uint4 hv = hp4[cch];
            f16x2 h0 = u2h(hv.x), h1 = u2h(hv.y), h2 = u2h(hv.z), h3 = u2h(hv.w);
            a0a = fdot2f(wlo[cch * 4 + 0], h0, a0a);
            a0b = fdot2f(wlo[cch * 4 + 1], h1, a0b);
            a0a = fdot2f(wlo[cch * 4 + 2], h2, a0a);
            a0b = fdot2f(wlo[cch * 4 + 3], h3, a0b);
            a1a = fdot2f(whi[cch * 4 + 0], h0, a1a);
            a1b = fdot2f(whi[cch * 4 + 1], h1, a1b);
            a1a = fdot2f(whi[cch * 4 + 2], h2, a1a);
            a1b = fdot2f(whi[cch * 4 + 3], h3, a1b);
        }
        // LDS-resident K range [192,256): 8 swizzled uint4 per row
        {
            const uint4* wl0 = (const uint4*)(Wl + g0 * 32);
            const uint4* wl1 = (const uint4*)(Wl + g1 * 32);
            #pragma unroll
            for (int c4 = 0; c4 < 8; ++c4) {
                uint4 hv = hp4[24 + c4];
                uint4 w0 = wl0[c4 ^ sw];
                uint4 w1 = wl1[c4 ^ sw];
                a0a = fdot2f(u2h(w0.x), u2h(hv.x), a0a);
                a0b = fdot2f(u2h(w0.y), u2h(hv.y), a0b);
                a0a = fdot2f(u2h(w0.z), u2h(hv.z), a0a);
                a0b = fdot2f(u2h(w0.w), u2h(hv.w), a0b);
                a1a = fdot2f(u2h(w1.x), u2h(hv.x), a1a);
                a1b = fdot2f(u2h(w1.y), u2h(hv.y), a1b);
                a1a = fdot2f(u2h(w1.z), u2h(hv.z), a1a);
                a1b = fdot2f(u2h(w1.w), u2h(hv.w), a1b);
            }
        }
        float G0 = xw0 + a0a + a0b;
        float G1 = xw1 + a1a + a1b;
        gate[g0] = G0; gate[g1] = G1;

        // c-mix (thread-local; overlaps with other waves' dots)
        float cmix = cst;
        if (tid < 256) {
            dcrun += del;
            float alpha = at / logf(2.718281828459045f + dcrun);
            cmix = alpha * c0 + (1.0f - alpha) * cst;
        }
        __syncthreads();
        if (tid < 256) {
            float gi = gate[j], gf = gate[256 + j], gg = gate[512 + j], go = gate[768 + j];
            cst = sigm(gf) * cmix + sigm(gi) * tanhf(gg);
            float h = sigm(go) * tanhf(cst);
            out[((size_t)b * Tn + t) * Hn + j] = h;
            float hn = __shfl_xor(h, 1);
            if ((j & 1) == 0) hpk[j >> 1] = packh2(h, hn);
        }
        __syncthreads();
    }
}

// ---------------------------------------------------------------------------
extern "C" void kernel_launch(void* const* d_in, const int* in_sizes, int n_in,
                              void* d_out, int out_size, void* d_ws, size_t ws_size,
                              hipStream_t stream) {
    const float* values = (const float*)d_in[0];
    const float* Deltas = (const float*)d_in[1];
    const float* W_att  = (const float*)d_in[2];
    const float* b_att  = (const float*)d_in[3];
    const float* W_ih   = (const float*)d_in[4];
    const float* W_hh   = (const float*)d_in[5];
    const float* b_ih   = (const float*)d_in[6];
    const float* b_hh   = (const float*)d_in[7];
    float* out = (float*)d_out;

    float* ws     = (float*)d_ws;
    float* xW     = ws;                                   // 32768*1024 = 33,554,432 f
    float* W_c    = xW + (size_t)32768 * 1024;            // 262,144 f
    float* bias_c = W_c + 1024 * 256;                     // 1,024 f
    float* vlin0  = bias_c + 1024;                        // 16,384 f
    float* atj    = vlin0 + 64 * 256;                     // 32,768 f
    // total ws: ~129.2 MiB

    k_wc<<<1024, 256, 0, stream>>>(W_ih, W_att, b_att, b_ih, b_hh, W_c, bias_c);
    k_vlin0<<<64, 256, 0, stream>>>(values, W_att, b_att, vlin0);
    k_atj<<<8192, 256, 0, stream>>>(values, vlin0, atj);
    k_gemm<<<dim3(16, 512), 256, 0, stream>>>(values, W_c, bias_c, xW);
    k_rec<<<64, 512, 131072 + 4096 + 512, stream>>>(xW, W_hh, Deltas, atj, out);
}